// Round 10
// baseline (416.352 us; speedup 1.0000x reference)
//
#include <hip/hip_runtime.h>
#include <stdint.h>

#define N_TOTAL 21840
#define NA      21888          // N_TOTAL rounded up to multiple of 64
#define W_MAX   342            // ceil(21840/64)
#define TOT_ENT 3753792u       // 64 * (342*343/2)  triangular CSR capacity
#define NMS_TH  0.3f
#define FINAL_TH 0.5f
#define NSLICE  8              // rank range-split factor

struct Inputs { const float* cls[6]; const float* reg[6]; };

// Closed-form CSR row base: row r (sorted pos) owns 342-(r>>6) slots.
__device__ __forceinline__ unsigned rowbase_u(unsigned r) {
  unsigned w = r >> 6, l = r & 63u;
  return 64u * (342u * w - (w * (w - 1u)) / 2u) + l * (342u - w);
}

// VALU-speed cross-lane u64 read (index wave-uniform) — no DS latency.
__device__ __forceinline__ unsigned long long rl_u64(unsigned long long x, int i) {
  unsigned lo = (unsigned)__builtin_amdgcn_readlane((int)(unsigned)(x & 0xffffffffull), i);
  unsigned hi = (unsigned)__builtin_amdgcn_readlane((int)(unsigned)(x >> 32), i);
  return ((unsigned long long)hi << 32) | lo;
}

// ---------------------------------------------------------------- decode ----
__global__ void decode_kernel(Inputs in,
                              float* __restrict__ dx1, float* __restrict__ dy1,
                              float* __restrict__ dx2, float* __restrict__ dy2,
                              float* __restrict__ dsc,
                              unsigned long long* __restrict__ ckey,
                              unsigned int* __restrict__ Mc,
                              unsigned int* __restrict__ rank32,
                              unsigned int* __restrict__ cnt,
                              float* __restrict__ out) {
#pragma clang fp contract(off)
  int gid = blockIdx.x * blockDim.x + threadIdx.x;
  if (gid >= N_TOTAL) return;
  rank32[gid] = 0u;
  cnt[gid] = 0u;
  if (gid < NA - N_TOTAL) cnt[N_TOTAL + gid] = 0u;
  int sc, local;
  if      (gid < 16384) { sc = 0; local = gid;         }
  else if (gid < 20480) { sc = 1; local = gid - 16384; }
  else if (gid < 21504) { sc = 2; local = gid - 20480; }
  else if (gid < 21760) { sc = 3; local = gid - 21504; }
  else if (gid < 21824) { sc = 4; local = gid - 21760; }
  else                  { sc = 5; local = gid - 21824; }
  const int Wd = 128 >> sc, stride = 4 << sc, HW = Wd * Wd;
  const int x = local & (Wd - 1), y = local >> (7 - sc);
  const float* cls = in.cls[sc];
  const float* reg = in.reg[sc];
  float c0 = cls[local], c1 = cls[HW + local];
  float m  = fmaxf(c0, c1);
  float e0 = expf(c0 - m), e1 = expf(c1 - m);
  float prob = e1 / (e0 + e1);
  float l0 = reg[local], l1 = reg[HW + local];
  float l2 = reg[2 * HW + local], l3 = reg[3 * HW + local];
  float sF  = (float)stride;
  float pcx = 0.5f * sF + (float)x * sF;
  float pcy = 0.5f * sF + (float)y * sF;
  float pwh = sF * 4.0f;
  float cx = pcx + ((l0 * 0.1f) * pwh);
  float cy = pcy + ((l1 * 0.1f) * pwh);
  float w  = pwh * expf(l2 * 0.2f);
  float h  = pwh * expf(l3 * 0.2f);
  float x1 = cx - w * 0.5f, y1 = cy - h * 0.5f;
  float x2 = x1 + w, y2 = y1 + h;
  dx1[gid] = x1; dy1[gid] = y1; dx2[gid] = x2; dy2[gid] = y2; dsc[gid] = prob;
  out[gid * 5 + 0] = 0.0f; out[gid * 5 + 1] = 0.0f; out[gid * 5 + 2] = 0.0f;
  out[gid * 5 + 3] = 0.0f; out[gid * 5 + 4] = 0.0f;
  // Only boxes with score > FINAL_TH can affect the output (suppression only
  // flows downward in score order, and only >FINAL_TH rows are exposed).
  if (prob > FINAL_TH) {
    unsigned int pos = atomicAdd(Mc, 1u);
    ckey[pos] = ((unsigned long long)__float_as_uint(prob) << 32) |
                (unsigned int)(~(unsigned int)gid);
  }
}

// ---------------------------------------------------------------- rank ------
// Count-rank with 8-way key-range split; packed atomicAdd join (measured-good).
__global__ void __launch_bounds__(256)
rank_kernel(const unsigned long long* __restrict__ ckey,
            const unsigned int* __restrict__ Mc,
            const float* __restrict__ dx1, const float* __restrict__ dy1,
            const float* __restrict__ dx2, const float* __restrict__ dy2,
            float* __restrict__ sx1, float* __restrict__ sy1,
            float* __restrict__ sx2, float* __restrict__ sy2,
            unsigned int* __restrict__ sorig,
            unsigned int* __restrict__ rank32) {
  __shared__ unsigned long long tile[256];
  const unsigned int M = *Mc;
  if (blockIdx.x * 256u >= M) return;
  const int t = (int)threadIdx.x;
  const int p = (int)blockIdx.x * 256 + t;
  unsigned long long mykey = (p < (int)M) ? ckey[p] : 0ull;
  const int S  = (int)((M + NSLICE - 1) / NSLICE);
  const int lo = (int)blockIdx.y * S;
  const int hi = min((int)M, lo + S);
  int partial = 0;
  const int nt = (hi > lo) ? ((hi - lo + 255) >> 8) : 0;
  for (int ti = 0; ti < nt; ++ti) {
    int j = lo + ti * 256 + t;
    tile[t] = (j < hi) ? ckey[j] : 0ull;
    __syncthreads();
#pragma unroll 8
    for (int q = 0; q < 256; ++q) partial += (tile[q] > mykey) ? 1 : 0;
    __syncthreads();
  }
  if (p < (int)M) {
    unsigned int pack = (unsigned int)partial | (1u << 24);
    unsigned int old  = atomicAdd(&rank32[p], pack);
    unsigned int newv = old + pack;
    if ((newv >> 24) == NSLICE) {
      int r = (int)(newv & 0xFFFFFF);
      unsigned int orig = ~(unsigned int)(mykey & 0xffffffffull);
      sx1[r] = dx1[orig]; sy1[r] = dy1[orig];
      sx2[r] = dx2[orig]; sy2[r] = dy2[orig];
      sorig[r] = orig;
    }
  }
}

// ---------------------------------------------------------------- pairs -----
// Sparse suppression structure (measured-good R7 form):
//   diag[r] = in-word bits; offd[r] = bits vs next word;
//   CSR rows rlJw/rlBits[rowbase(r)+k], k < cnt[r], for cw >= rw+2, bits != 0.
__global__ void __launch_bounds__(1024)
pairs_kernel(const float* __restrict__ sx1, const float* __restrict__ sy1,
             const float* __restrict__ sx2, const float* __restrict__ sy2,
             const unsigned int* __restrict__ Mc,
             unsigned long long* __restrict__ diag,
             unsigned long long* __restrict__ offd,
             unsigned int* __restrict__ cnt,
             unsigned short* __restrict__ rlJw,
             unsigned long long* __restrict__ rlBits) {
#pragma clang fp contract(off)
  const int M = (int)*Mc;
  const int W = (M + 63) >> 6;
  const int rw = (int)blockIdx.y;
  const int cwg = (int)blockIdx.x << 4;
  if (rw >= W || cwg >= W || cwg + 15 < rw) return;
  const int t = (int)threadIdx.x;
  const int g = t >> 6, l = t & 63;
  const int cw = cwg + g;
  __shared__ float cx1[1024], cy1[1024], cx2[1024], cy2[1024], car[1024];
  {
    int c = (cw << 6) + l;
    if (cw < W && c < M) {
      float a = sx1[c], b = sy1[c], d = sx2[c], e = sy2[c];
      cx1[t] = a; cy1[t] = b; cx2[t] = d; cy2[t] = e;
      car[t] = (d - a + 1.0f) * (e - b + 1.0f);
    }
  }
  __syncthreads();
  if (cw >= W || cw < rw) return;
  const int r = (rw << 6) + l;
  unsigned long long bits = 0ull;
  if (r < M) {
    float ax1 = sx1[r], ay1 = sy1[r], ax2 = sx2[r], ay2 = sy2[r];
    float aarea = (ax2 - ax1 + 1.0f) * (ay2 - ay1 + 1.0f);
    const int cmax = min(64, M - (cw << 6));
    const int sb = g << 6;
    for (int cc = 0; cc < cmax; ++cc) {
      int cg = (cw << 6) + cc;
      if (cg > r) {
        float xx1 = fmaxf(ax1, cx1[sb + cc]);
        float yy1 = fmaxf(ay1, cy1[sb + cc]);
        float xx2 = fminf(ax2, cx2[sb + cc]);
        float yy2 = fminf(ay2, cy2[sb + cc]);
        float ww = fmaxf(xx2 - xx1 + 1.0f, 0.0f);
        float hh = fmaxf(yy2 - yy1 + 1.0f, 0.0f);
        float inter = ww * hh;
        float iou = inter / (aarea + car[sb + cc] - inter);
        if (iou > NMS_TH) bits |= (1ull << cc);
      }
    }
  }
  if (cw == rw)            diag[r] = bits;
  else if (cw == rw + 1)   offd[r] = bits;
  else if (bits != 0ull) {
    unsigned k = atomicAdd(&cnt[r], 1u);
    unsigned b = rowbase_u((unsigned)r) + k;
    rlJw[b]   = (unsigned short)cw;
    rlBits[b] = bits;
  }
}

// ---------------------------------------------------------------- scan ------
// SINGLE-WAVE greedy scan: wave 0 does the whole scan with ZERO barriers.
// Lane l owns row (w<<6)+l at step w: it scans (readlane, in-register),
// carries w->w+1 via LDS atomicOr, and applies its own row's CSR pushes
// (4 prefetched entries, predicated by cnt; rare >4 tail direct). Program
// order within the wave replaces all inter-wave synchronization (pushes to
// sup[jw>=w+1] at step w are drained by lgkmcnt before step jw's ds_read).
// Waves 1-15 park at __syncthreads and join only for the output scatter.
__global__ void __launch_bounds__(1024)
scan_kernel(const unsigned long long* __restrict__ diag,
            const unsigned long long* __restrict__ offd,
            const unsigned int* __restrict__ cnt,
            const unsigned short* __restrict__ rlJw,
            const unsigned long long* __restrict__ rlBits,
            const unsigned int* __restrict__ sorig,
            const unsigned int* __restrict__ Mc,
            const float* __restrict__ dx1, const float* __restrict__ dy1,
            const float* __restrict__ dx2, const float* __restrict__ dy2,
            const float* __restrict__ dsc,
            float* __restrict__ out) {
  __shared__ unsigned long long sup[W_MAX];
  __shared__ unsigned long long kmls[W_MAX];
  const int t = (int)threadIdx.x;
  const int g = t >> 6, l = t & 63;
  const int M = (int)*Mc;
  const int W = (M + 63) >> 6;
  for (int i = t; i < W_MAX; i += 1024) { sup[i] = 0ull; kmls[i] = 0ull; }
  __syncthreads();

  if (g == 0) {
    // ---- prefetch state (2 steps ahead; named scalars) ----
    unsigned long long rb_cur = (0 < W) ? diag[l] : 0ull;
    unsigned long long rb_nxt = (1 < W) ? diag[64 + l] : 0ull;
    unsigned long long pv_cur = (1 < W) ? offd[l] : 0ull;
    unsigned long long pv_nxt = (2 < W) ? offd[64 + l] : 0ull;
    unsigned c0 = (0 < W) ? cnt[l] : 0u;
    unsigned c1 = (1 < W) ? cnt[64 + l] : 0u;
    unsigned c2 = (2 < W) ? cnt[128 + l] : 0u;
    unsigned c3 = (3 < W) ? cnt[192 + l] : 0u;
    unsigned long long eb0c, eb1c, eb2c, eb3c, eb0n, eb1n, eb2n, eb3n;
    unsigned ej0c, ej1c, ej2c, ej3c, ej0n, ej1n, ej2n, ej3n;
    {   // entries for w=0 (pred c0) and w=1 (pred c1)
      unsigned rb0_ = rowbase_u((unsigned)l);
      unsigned rb1_ = rowbase_u((unsigned)(64 + l));
      bool ok1 = (1 < W);
#define LD_ENT(EB, EJ, BASE, CC, K, OKW) { \
      bool ld = (OKW) && ((K) < (CC)); unsigned i = ld ? ((BASE) + (K)) : 0u; \
      EB = ld ? rlBits[i] : 0ull; EJ = ld ? (unsigned)rlJw[i] : 0u; }
      LD_ENT(eb0c, ej0c, rb0_, c0, 0u, true)
      LD_ENT(eb1c, ej1c, rb0_, c0, 1u, true)
      LD_ENT(eb2c, ej2c, rb0_, c0, 2u, true)
      LD_ENT(eb3c, ej3c, rb0_, c0, 3u, true)
      LD_ENT(eb0n, ej0n, rb1_, c1, 0u, ok1)
      LD_ENT(eb1n, ej1n, rb1_, c1, 1u, ok1)
      LD_ENT(eb2n, ej2n, rb1_, c1, 2u, ok1)
      LD_ENT(eb3n, ej3n, rb1_, c1, 3u, ok1)
    }

    for (int w = 0; w < W; ++w) {
      const int base = w << 6;
      unsigned long long supw = sup[w];        // includes all earlier pushes
      unsigned long long rowbits = rb_cur;
      unsigned long long pvc = pv_cur;
      unsigned long long ub0 = eb0c, ub1 = eb1c, ub2 = eb2c, ub3 = eb3c;
      unsigned uj0 = ej0c, uj1 = ej1c, uj2 = ej2c, uj3 = ej3c;
      unsigned ccur = c0;
      // rotate
      rb_cur = rb_nxt; pv_cur = pv_nxt;
      eb0c = eb0n; eb1c = eb1n; eb2c = eb2n; eb3c = eb3n;
      ej0c = ej0n; ej1c = ej1n; ej2c = ej2n; ej3c = ej3n;
      c0 = c1; c1 = c2; c2 = c3;
      // issue loads for step w+2 (rows base+128+l) and cnt for w+4
      {
        int rn = base + 128 + l;
        bool okw = (w + 2 < W);
        rb_nxt = okw ? diag[rn] : 0ull;
        pv_nxt = (w + 3 < W) ? offd[rn] : 0ull;
        c3 = (w + 4 < W) ? cnt[base + 256 + l] : 0u;
        unsigned cb = c1;                      // cnt for w+2 after rotation
        unsigned rbn = okw ? rowbase_u((unsigned)rn) : 0u;
        LD_ENT(eb0n, ej0n, rbn, cb, 0u, okw)
        LD_ENT(eb1n, ej1n, rbn, cb, 1u, okw)
        LD_ENT(eb2n, ej2n, rbn, cb, 2u, okw)
        LD_ENT(eb3n, ej3n, rbn, cb, 3u, okw)
      }
#undef LD_ENT
#define LD_ENT(EB, EJ, BASE, CC, K, OKW) { \
      bool ld = (OKW) && ((K) < (CC)); unsigned i = ld ? ((BASE) + (K)) : 0u; \
      EB = ld ? rlBits[i] : 0ull; EJ = ld ? (unsigned)rlJw[i] : 0u; }
      // ---- greedy scan of word w ----
      unsigned long long nz = __ballot(rowbits != 0ull);
      const int n = min(64, M - base);
      unsigned long long wordmask = (n >= 64) ? ~0ull : ((1ull << n) - 1ull);
      unsigned long long pend = (~supw) & wordmask;
      unsigned long long kept = 0ull;
      unsigned long long act = pend & nz;
      while (act) {                     // iterations = #kept rows w/ bits
        int i = __builtin_ctzll(act);   // uniform
        unsigned long long upto = (2ull << i) - 1ull;
        kept |= pend & upto;
        unsigned long long ri = rl_u64(rowbits, i);   // VALU readlane
        pend &= ~upto;
        pend &= ~ri;
        act = pend & nz;
      }
      kept |= pend;
      if (l == 0) kmls[w] = kept;
      // ---- apply pushes for kept rows (same wave, program order) ----
      if ((kept >> l) & 1ull) {
        if (pvc != 0ull && (w + 1 < W)) atomicOr(&sup[w + 1], pvc);
        if (0u < ccur) atomicOr(&sup[uj0], ub0);
        if (1u < ccur) atomicOr(&sup[uj1], ub1);
        if (2u < ccur) atomicOr(&sup[uj2], ub2);
        if (3u < ccur) atomicOr(&sup[uj3], ub3);
        if (ccur > 4u) {               // rare high-degree tail
          unsigned rb_ = rowbase_u((unsigned)(base + l));
          for (unsigned k = 4u; k < ccur; ++k) {
            unsigned ii = rb_ + k;
            atomicOr(&sup[rlJw[ii]], rlBits[ii]);
          }
        }
      }
    }
  }
  __syncthreads();

  // scatter kept rows into the (pre-zeroed) output — all 16 waves
  for (int i = t; i < (W << 6); i += 1024) {
    if ((kmls[i >> 6] >> (i & 63)) & 1ull) {
      unsigned int orig = sorig[i];
      out[(size_t)orig * 5 + 0] = dx1[orig];
      out[(size_t)orig * 5 + 1] = dy1[orig];
      out[(size_t)orig * 5 + 2] = dx2[orig];
      out[(size_t)orig * 5 + 3] = dy2[orig];
      out[(size_t)orig * 5 + 4] = dsc[orig];
    }
  }
}

// ---------------------------------------------------------------- launch ----
extern "C" void kernel_launch(void* const* d_in, const int* in_sizes, int n_in,
                              void* d_out, int out_size, void* d_ws, size_t ws_size,
                              hipStream_t stream) {
  (void)in_sizes; (void)n_in; (void)out_size; (void)ws_size;

  Inputs in;
  for (int i = 0; i < 6; ++i) {
    in.cls[i] = (const float*)d_in[2 * i];
    in.reg[i] = (const float*)d_in[2 * i + 1];
  }

  char* ws = (char*)d_ws;
  size_t o = 0;
  float* dx1 = (float*)(ws + o); o += (size_t)NA * 4;
  float* dy1 = (float*)(ws + o); o += (size_t)NA * 4;
  float* dx2 = (float*)(ws + o); o += (size_t)NA * 4;
  float* dy2 = (float*)(ws + o); o += (size_t)NA * 4;
  float* dsc = (float*)(ws + o); o += (size_t)NA * 4;
  unsigned long long* ckey = (unsigned long long*)(ws + o); o += (size_t)NA * 8;
  float* sx1 = (float*)(ws + o); o += (size_t)NA * 4;
  float* sy1 = (float*)(ws + o); o += (size_t)NA * 4;
  float* sx2 = (float*)(ws + o); o += (size_t)NA * 4;
  float* sy2 = (float*)(ws + o); o += (size_t)NA * 4;
  unsigned int* sorig = (unsigned int*)(ws + o); o += (size_t)NA * 4;
  unsigned int* rank32 = (unsigned int*)(ws + o); o += (size_t)NA * 4;
  unsigned int* cnt = (unsigned int*)(ws + o); o += (size_t)NA * 4;
  unsigned int* Mc = (unsigned int*)(ws + o); o += 64;
  o = (o + 511) & ~(size_t)511;
  unsigned long long* diag = (unsigned long long*)(ws + o); o += (size_t)NA * 8;
  unsigned long long* offd = (unsigned long long*)(ws + o); o += (size_t)NA * 8;
  unsigned long long* rlBits = (unsigned long long*)(ws + o); o += (size_t)TOT_ENT * 8;
  unsigned short* rlJw = (unsigned short*)(ws + o); o += (size_t)TOT_ENT * 2;

  const int nb = (N_TOTAL + 255) / 256;  // 86

  (void)hipMemsetAsync((void*)Mc, 0, 64, stream);
  decode_kernel<<<nb, 256, 0, stream>>>(in, dx1, dy1, dx2, dy2, dsc, ckey, Mc,
                                        rank32, cnt, (float*)d_out);
  rank_kernel<<<dim3(nb, NSLICE), 256, 0, stream>>>(ckey, Mc, dx1, dy1, dx2, dy2,
                                                    sx1, sy1, sx2, sy2, sorig,
                                                    rank32);
  pairs_kernel<<<dim3(22, W_MAX), 1024, 0, stream>>>(sx1, sy1, sx2, sy2, Mc,
                                                     diag, offd, cnt, rlJw, rlBits);
  scan_kernel<<<1, 1024, 0, stream>>>(diag, offd, cnt, rlJw, rlBits, sorig, Mc,
                                      dx1, dy1, dx2, dy2, dsc, (float*)d_out);
}